// Round 17
// baseline (112.933 us; speedup 1.0000x reference)
//
#include <hip/hip_runtime.h>
#include <math.h>

#define TPB 256

constexpr int Bn    = 131072;
constexpr float LOG2E = 1.4426950408889634f;

typedef float v2f __attribute__((ext_vector_type(2)));

__global__ __launch_bounds__(TPB)
void gat_ppo_kernel(const float* __restrict__ xg,
                    const float* __restrict__ adjg,
                    const float* __restrict__ Wg,
                    const float* __restrict__ ahg,
                    const float* __restrict__ wog,
                    const float* __restrict__ aog,
                    const float* __restrict__ muWg,
                    const float* __restrict__ mubg,
                    const float* __restrict__ sgWg,
                    const float* __restrict__ sgbg,
                    const float* __restrict__ vWg,
                    const float* __restrict__ vbg,
                    float* __restrict__ outg)
{
    // R12 structure (best: merged f-pass + concurrent head phases), with ONE
    // change: all weight reads are forced through VMEM (global_load) instead
    // of s_load. Scalar-mem results return out-of-order and share lgkmcnt
    // with in-order DS ops, forcing conservative lgkmcnt(0) drains around
    // every tile/shuffle op; routing weights to vmcnt decouples the pipes.
    __shared__ float4 tile[4][3][200];

    const int lb = threadIdx.x;
    const int w  = lb >> 6;
    const int g  = (lb & 63) >> 3;
    const int n  = lb & 7;
    const size_t t = (size_t)blockIdx.x * TPB + lb;   // global row = b*8 + n

    // Opaque zero in a VGPR: weight pointers become vector-based -> VMEM.
    unsigned vz;
    asm volatile("v_mov_b32 %0, 0" : "=v"(vz));

    const v2f*   Wp   = (const v2f*)Wg + vz;
    const float* ahv  = ahg  + vz;
    const float* wov  = wog  + vz;
    const float* aov  = aog  + vz;
    const v2f*   muWp = (const v2f*)muWg + vz;
    const v2f*   sgWp = (const v2f*)sgWg + vz;
    const v2f*   vWp  = (const v2f*)vWg  + vz;
    const float* mubv = mubg + vz;
    const float* sgbv = sgbg + vz;
    const float* vbv  = vbg  + vz;

    // ---- adj row -> 8-bit mask ----
    unsigned amask;
    {
        const float4* a4 = (const float4*)(adjg) + t * 2;
        float4 a0 = a4[0], a1 = a4[1];
        amask =  (unsigned)(a0.x > 0.0f)
              | ((unsigned)(a0.y > 0.0f) << 1)
              | ((unsigned)(a0.z > 0.0f) << 2)
              | ((unsigned)(a0.w > 0.0f) << 3)
              | ((unsigned)(a1.x > 0.0f) << 4)
              | ((unsigned)(a1.y > 0.0f) << 5)
              | ((unsigned)(a1.z > 0.0f) << 6)
              | ((unsigned)(a1.w > 0.0f) << 7);
    }

    // ---- merged f-pass: all 3 heads' Wh accumulators in one x stream ----
    v2f acc[3][4];
    #pragma unroll
    for (int h = 0; h < 3; ++h)
        #pragma unroll
        for (int o2 = 0; o2 < 4; ++o2) acc[h][o2] = (v2f){0.0f, 0.0f};

    {
        const float2* xr = (const float2*)(xg + t * 30);
        #pragma unroll
        for (int k = 0; k < 15; ++k) {
            float2 v = xr[k];
            #pragma unroll
            for (int e = 0; e < 2; ++e) {
                const int f = 2 * k + e;
                const float xf = e ? v.y : v.x;
                v2f xv = (v2f){xf, xf};
                #pragma unroll
                for (int h = 0; h < 3; ++h)
                    #pragma unroll
                    for (int o2 = 0; o2 < 4; ++o2)
                        acc[h][o2] = __builtin_elementwise_fma(xv, Wp[h * 120 + f * 4 + o2], acc[h][o2]);
            }
        }
    }

    // ---- scores for all heads (log2 domain) ----
    float f1h[3], f2h[3];
    #pragma unroll
    for (int h = 0; h < 3; ++h) {
        float s1 = 0.0f, s2 = 0.0f;
        #pragma unroll
        for (int o2 = 0; o2 < 4; ++o2) {
            s1 = fmaf(acc[h][o2].x, ahv[h * 16 + 2 * o2],     s1);
            s1 = fmaf(acc[h][o2].y, ahv[h * 16 + 2 * o2 + 1], s1);
            s2 = fmaf(acc[h][o2].x, ahv[h * 16 + 8 + 2 * o2],     s2);
            s2 = fmaf(acc[h][o2].y, ahv[h * 16 + 8 + 2 * o2 + 1], s2);
        }
        f1h[h] = s1 * LOG2E;
        f2h[h] = s2 * LOG2E;
    }

    // ---- publish all 3 heads' Wh rows (6 x ds_write_b128) ----
    #pragma unroll
    for (int h = 0; h < 3; ++h) {
        tile[w][h][g * 25 + n * 3]     = (float4){acc[h][0].x, acc[h][0].y, acc[h][1].x, acc[h][1].y};
        tile[w][h][g * 25 + n * 3 + 1] = (float4){acc[h][2].x, acc[h][2].y, acc[h][3].x, acc[h][3].y};
    }
    // Pin program order: cross-lane write->read dependency is invisible to
    // alias analysis (round-9 race mechanism). Per-wave in-order LDS pipe
    // guarantees the hardware side once order is pinned.
    asm volatile("" ::: "memory");
    __builtin_amdgcn_sched_barrier(0);

    // ---- 3 softmaxes interleaved (independent shfl + exp chains) ----
    float p[3][8];
    float s[3] = {0.0f, 0.0f, 0.0f};
    #pragma unroll
    for (int m = 0; m < 8; ++m) {
        const bool on = (amask >> m) & 1u;
        #pragma unroll
        for (int h = 0; h < 3; ++h) {
            float ev = f1h[h] + __shfl(f2h[h], m, 8);
            ev = fmaxf(ev, 0.2f * ev);                 // leaky (log2-scaled)
            float pe = on ? __builtin_amdgcn_exp2f(ev) : 0.0f;
            p[h][m] = pe; s[h] += pe;
        }
    }

    // ---- 3 aggregations: independent broadcast b128 reads ----
    v2f hacc[3][4];
    #pragma unroll
    for (int h = 0; h < 3; ++h)
        #pragma unroll
        for (int o2 = 0; o2 < 4; ++o2) hacc[h][o2] = (v2f){0.0f, 0.0f};

    #pragma unroll
    for (int m = 0; m < 8; ++m) {
        #pragma unroll
        for (int h = 0; h < 3; ++h) {
            float4 lo = tile[w][h][g * 25 + m * 3];
            float4 hi = tile[w][h][g * 25 + m * 3 + 1];
            v2f av = (v2f){p[h][m], p[h][m]};
            hacc[h][0] = __builtin_elementwise_fma(av, (v2f){lo.x, lo.y}, hacc[h][0]);
            hacc[h][1] = __builtin_elementwise_fma(av, (v2f){lo.z, lo.w}, hacc[h][1]);
            hacc[h][2] = __builtin_elementwise_fma(av, (v2f){hi.x, hi.y}, hacc[h][2]);
            hacc[h][3] = __builtin_elementwise_fma(av, (v2f){hi.z, hi.w}, hacc[h][3]);
        }
    }

    // ---- elu + W_out fold ----
    float wh2 = 0.0f;
    #pragma unroll
    for (int h = 0; h < 3; ++h) {
        float rs = 1.0f / s[h];
        #pragma unroll
        for (int o2 = 0; o2 < 4; ++o2) {
            #pragma unroll
            for (int j = 0; j < 2; ++j) {
                float hv = hacc[h][o2][j] * rs;
                hv = (hv > 0.0f) ? hv : (__expf(hv) - 1.0f);   // elu
                wh2 = fmaf(hv, wov[h * 8 + 2 * o2 + j], wh2);  // h @ W_out
            }
        }
    }

    // ---- second GAT layer on Wh2 (log2 domain, deferred norm) ----
    const float a0c = aov[0] * LOG2E, a1c = aov[1] * LOG2E;
    float wh2a[8];
    #pragma unroll
    for (int m = 0; m < 8; ++m) wh2a[m] = __shfl(wh2, m, 8);

    float g1 = a0c * wh2;
    float s2s = 0.0f;
    float og = 0.0f;
    #pragma unroll
    for (int m = 0; m < 8; ++m) {
        float ev = fmaf(a1c, wh2a[m], g1);
        ev = fmaxf(ev, 0.2f * ev);
        float pe = ((amask >> m) & 1u) ? __builtin_amdgcn_exp2f(ev) : 0.0f;
        s2s += pe;
        og = fmaf(pe, wh2a[m], og);
    }
    og /= s2s;
    float g2v = (og > 0.0f) ? og : (__expf(og) - 1.0f);   // elu -> g[b][n]

    // ---- MLP heads: mu, sigma (per node), value (per batch) ----
    v2f gp[4];
    #pragma unroll
    for (int m = 0; m < 4; ++m)
        gp[m] = (v2f){__shfl(g2v, 2 * m, 8), __shfl(g2v, 2 * m + 1, 8)};

    v2f ma = (v2f){0.0f, 0.0f}, sa = (v2f){0.0f, 0.0f}, va = (v2f){0.0f, 0.0f};
    #pragma unroll
    for (int k = 0; k < 4; ++k) {
        ma = __builtin_elementwise_fma(gp[k], muWp[n * 4 + k], ma);
        sa = __builtin_elementwise_fma(gp[k], sgWp[n * 4 + k], sa);
        va = __builtin_elementwise_fma(gp[k], vWp[k],          va);
    }
    float mu = ma.x + ma.y + mubv[n];
    float sg = sa.x + sa.y + sgbv[n];
    float vv = va.x + va.y + vbv[0];

    mu = 1.0f / (1.0f + __expf(-mu));                               // sigmoid
    sg = fmaxf(sg, 0.0f) + log1pf(__expf(-fabsf(sg))) + 0.001f;     // softplus + 1e-3

    outg[t]          = mu;
    outg[Bn * 8 + t] = sg;
    if (n == 0) outg[Bn * 16 + (t >> 3)] = vv;
}

extern "C" void kernel_launch(void* const* d_in, const int* in_sizes, int n_in,
                              void* d_out, int out_size, void* d_ws, size_t ws_size,
                              hipStream_t stream) {
    const float* xg   = (const float*)d_in[0];
    const float* adjg = (const float*)d_in[1];
    const float* Wg   = (const float*)d_in[2];
    const float* ahg  = (const float*)d_in[3];
    const float* wog  = (const float*)d_in[4];
    const float* aog  = (const float*)d_in[5];
    const float* muW  = (const float*)d_in[6];
    const float* mub  = (const float*)d_in[7];
    const float* sgW  = (const float*)d_in[8];
    const float* sgb  = (const float*)d_in[9];
    const float* vW   = (const float*)d_in[10];
    const float* vb   = (const float*)d_in[11];
    float* outg = (float*)d_out;

    dim3 grid(Bn * 8 / TPB);  // 4096 blocks of 256 threads; 8 lanes per graph
    gat_ppo_kernel<<<grid, TPB, 0, stream>>>(xg, adjg, Wg, ahg, wog, aog,
                                             muW, mub, sgW, sgb, vW, vb, outg);
}

// Round 18
// 61.932 us; speedup vs baseline: 1.8235x; 1.8235x over previous
//
#include <hip/hip_runtime.h>
#include <math.h>

#define TPB 256

constexpr int Bn    = 131072;
constexpr float LOG2E = 1.4426950408889634f;

typedef float v2f __attribute__((ext_vector_type(2)));

__global__ __launch_bounds__(TPB)
void gat_ppo_kernel(const float* __restrict__ xg,
                    const float* __restrict__ adjg,
                    const float* __restrict__ Wg,
                    const float* __restrict__ ahg,
                    const float* __restrict__ wog,
                    const float* __restrict__ aog,
                    const float* __restrict__ muWg,
                    const float* __restrict__ mubg,
                    const float* __restrict__ sgWg,
                    const float* __restrict__ sgbg,
                    const float* __restrict__ vWg,
                    const float* __restrict__ vbg,
                    float* __restrict__ outg)
{
    // R12 structure with ONE variable changed: all weights staged into LDS
    // once per block (3.8 KB), body reads them as broadcast ds_read (in-order
    // -> precise lgkmcnt waits; no s_load streaming, no OOO scalar results
    // mixing into the DS wait counter). W reordered to [f][h*8+o] so each
    // f-step reads 24 contiguous floats (6 x b128).
    __shared__ __align__(16) float wl[948];
    __shared__ float4 tile[4][3][200];

    const int lb = threadIdx.x;
    const int w  = lb >> 6;
    const int g  = (lb & 63) >> 3;
    const int n  = lb & 7;
    const size_t t = (size_t)blockIdx.x * TPB + lb;   // global row = b*8 + n

    // ---- stage all weights into LDS (once per block) ----
    for (int i = lb; i < 720; i += TPB) {
        int f = i / 24, c = i % 24, h = c >> 3, o = c & 7;
        wl[i] = Wg[h * 240 + f * 8 + o];
    }
    if (lb < 48) wl[720 + lb] = ahg[lb];
    if (lb < 24) wl[768 + lb] = wog[lb];
    if (lb < 2)  wl[792 + lb] = aog[lb];
    if (lb < 64) wl[794 + lb] = muWg[lb];
    if (lb < 64) wl[858 + lb] = sgWg[lb];
    if (lb < 8)  wl[922 + lb] = vWg[lb];
    if (lb < 8)  wl[930 + lb] = mubg[lb];
    if (lb < 8)  wl[938 + lb] = sgbg[lb];
    if (lb == 0) wl[946] = vbg[0];
    __syncthreads();

    const v2f*   Wlv  = (const v2f*)wl;          // [f][12 v2f]
    const float* ahl  = wl + 720;
    const float* wol  = wl + 768;
    const float* aol  = wl + 792;
    const v2f*   muWl = (const v2f*)(wl + 794);
    const v2f*   sgWl = (const v2f*)(wl + 858);
    const v2f*   vWl  = (const v2f*)(wl + 922);
    const float* mubl = wl + 930;
    const float* sgbl = wl + 938;

    // ---- adj row -> 8-bit mask ----
    unsigned amask;
    {
        const float4* a4 = (const float4*)(adjg) + t * 2;
        float4 a0 = a4[0], a1 = a4[1];
        amask =  (unsigned)(a0.x > 0.0f)
              | ((unsigned)(a0.y > 0.0f) << 1)
              | ((unsigned)(a0.z > 0.0f) << 2)
              | ((unsigned)(a0.w > 0.0f) << 3)
              | ((unsigned)(a1.x > 0.0f) << 4)
              | ((unsigned)(a1.y > 0.0f) << 5)
              | ((unsigned)(a1.z > 0.0f) << 6)
              | ((unsigned)(a1.w > 0.0f) << 7);
    }

    // ---- merged f-pass: all 3 heads' Wh accumulators in one x stream ----
    v2f acc[3][4];
    #pragma unroll
    for (int h = 0; h < 3; ++h)
        #pragma unroll
        for (int o2 = 0; o2 < 4; ++o2) acc[h][o2] = (v2f){0.0f, 0.0f};

    {
        const float2* xr = (const float2*)(xg + t * 30);
        #pragma unroll
        for (int k = 0; k < 15; ++k) {
            float2 v = xr[k];
            #pragma unroll
            for (int e = 0; e < 2; ++e) {
                const int f = 2 * k + e;
                const float xf = e ? v.y : v.x;
                v2f xv = (v2f){xf, xf};
                #pragma unroll
                for (int h = 0; h < 3; ++h)
                    #pragma unroll
                    for (int o2 = 0; o2 < 4; ++o2)
                        acc[h][o2] = __builtin_elementwise_fma(xv, Wlv[f * 12 + h * 4 + o2], acc[h][o2]);
            }
        }
    }

    // ---- scores for all heads (log2 domain) ----
    float f1h[3], f2h[3];
    #pragma unroll
    for (int h = 0; h < 3; ++h) {
        float s1 = 0.0f, s2 = 0.0f;
        #pragma unroll
        for (int o2 = 0; o2 < 4; ++o2) {
            s1 = fmaf(acc[h][o2].x, ahl[h * 16 + 2 * o2],     s1);
            s1 = fmaf(acc[h][o2].y, ahl[h * 16 + 2 * o2 + 1], s1);
            s2 = fmaf(acc[h][o2].x, ahl[h * 16 + 8 + 2 * o2],     s2);
            s2 = fmaf(acc[h][o2].y, ahl[h * 16 + 8 + 2 * o2 + 1], s2);
        }
        f1h[h] = s1 * LOG2E;
        f2h[h] = s2 * LOG2E;
    }

    // ---- publish all 3 heads' Wh rows (6 x ds_write_b128) ----
    #pragma unroll
    for (int h = 0; h < 3; ++h) {
        tile[w][h][g * 25 + n * 3]     = (float4){acc[h][0].x, acc[h][0].y, acc[h][1].x, acc[h][1].y};
        tile[w][h][g * 25 + n * 3 + 1] = (float4){acc[h][2].x, acc[h][2].y, acc[h][3].x, acc[h][3].y};
    }
    // Pin program order: cross-lane write->read dependency is invisible to
    // alias analysis (round-9 race mechanism). Per-wave in-order LDS pipe
    // guarantees the hardware side once order is pinned.
    asm volatile("" ::: "memory");
    __builtin_amdgcn_sched_barrier(0);

    // ---- 3 softmaxes interleaved (independent shfl + exp chains) ----
    float p[3][8];
    float s[3] = {0.0f, 0.0f, 0.0f};
    #pragma unroll
    for (int m = 0; m < 8; ++m) {
        const bool on = (amask >> m) & 1u;
        #pragma unroll
        for (int h = 0; h < 3; ++h) {
            float ev = f1h[h] + __shfl(f2h[h], m, 8);
            ev = fmaxf(ev, 0.2f * ev);                 // leaky (log2-scaled)
            float pe = on ? __builtin_amdgcn_exp2f(ev) : 0.0f;
            p[h][m] = pe; s[h] += pe;
        }
    }

    // ---- 3 aggregations: independent broadcast b128 reads ----
    v2f hacc[3][4];
    #pragma unroll
    for (int h = 0; h < 3; ++h)
        #pragma unroll
        for (int o2 = 0; o2 < 4; ++o2) hacc[h][o2] = (v2f){0.0f, 0.0f};

    #pragma unroll
    for (int m = 0; m < 8; ++m) {
        #pragma unroll
        for (int h = 0; h < 3; ++h) {
            float4 lo = tile[w][h][g * 25 + m * 3];
            float4 hi = tile[w][h][g * 25 + m * 3 + 1];
            v2f av = (v2f){p[h][m], p[h][m]};
            hacc[h][0] = __builtin_elementwise_fma(av, (v2f){lo.x, lo.y}, hacc[h][0]);
            hacc[h][1] = __builtin_elementwise_fma(av, (v2f){lo.z, lo.w}, hacc[h][1]);
            hacc[h][2] = __builtin_elementwise_fma(av, (v2f){hi.x, hi.y}, hacc[h][2]);
            hacc[h][3] = __builtin_elementwise_fma(av, (v2f){hi.z, hi.w}, hacc[h][3]);
        }
    }

    // ---- elu + W_out fold ----
    float wh2 = 0.0f;
    #pragma unroll
    for (int h = 0; h < 3; ++h) {
        float rs = 1.0f / s[h];
        #pragma unroll
        for (int o2 = 0; o2 < 4; ++o2) {
            #pragma unroll
            for (int j = 0; j < 2; ++j) {
                float hv = hacc[h][o2][j] * rs;
                hv = (hv > 0.0f) ? hv : (__expf(hv) - 1.0f);   // elu
                wh2 = fmaf(hv, wol[h * 8 + 2 * o2 + j], wh2);  // h @ W_out
            }
        }
    }

    // ---- second GAT layer on Wh2 (log2 domain, deferred norm) ----
    const float a0c = aol[0] * LOG2E, a1c = aol[1] * LOG2E;
    float wh2a[8];
    #pragma unroll
    for (int m = 0; m < 8; ++m) wh2a[m] = __shfl(wh2, m, 8);

    float g1 = a0c * wh2;
    float s2s = 0.0f;
    float og = 0.0f;
    #pragma unroll
    for (int m = 0; m < 8; ++m) {
        float ev = fmaf(a1c, wh2a[m], g1);
        ev = fmaxf(ev, 0.2f * ev);
        float pe = ((amask >> m) & 1u) ? __builtin_amdgcn_exp2f(ev) : 0.0f;
        s2s += pe;
        og = fmaf(pe, wh2a[m], og);
    }
    og /= s2s;
    float g2v = (og > 0.0f) ? og : (__expf(og) - 1.0f);   // elu -> g[b][n]

    // ---- MLP heads: mu, sigma (per node), value (per batch) ----
    v2f gp[4];
    #pragma unroll
    for (int m = 0; m < 4; ++m)
        gp[m] = (v2f){__shfl(g2v, 2 * m, 8), __shfl(g2v, 2 * m + 1, 8)};

    v2f ma = (v2f){0.0f, 0.0f}, sa = (v2f){0.0f, 0.0f}, va = (v2f){0.0f, 0.0f};
    #pragma unroll
    for (int k = 0; k < 4; ++k) {
        ma = __builtin_elementwise_fma(gp[k], muWl[n * 4 + k], ma);
        sa = __builtin_elementwise_fma(gp[k], sgWl[n * 4 + k], sa);
        va = __builtin_elementwise_fma(gp[k], vWl[k],          va);
    }
    float mu = ma.x + ma.y + mubl[n];
    float sg = sa.x + sa.y + sgbl[n];
    float vv = va.x + va.y + wl[946];

    mu = 1.0f / (1.0f + __expf(-mu));                               // sigmoid
    sg = fmaxf(sg, 0.0f) + log1pf(__expf(-fabsf(sg))) + 0.001f;     // softplus + 1e-3

    outg[t]          = mu;
    outg[Bn * 8 + t] = sg;
    if (n == 0) outg[Bn * 16 + (t >> 3)] = vv;
}

extern "C" void kernel_launch(void* const* d_in, const int* in_sizes, int n_in,
                              void* d_out, int out_size, void* d_ws, size_t ws_size,
                              hipStream_t stream) {
    const float* xg   = (const float*)d_in[0];
    const float* adjg = (const float*)d_in[1];
    const float* Wg   = (const float*)d_in[2];
    const float* ahg  = (const float*)d_in[3];
    const float* wog  = (const float*)d_in[4];
    const float* aog  = (const float*)d_in[5];
    const float* muW  = (const float*)d_in[6];
    const float* mub  = (const float*)d_in[7];
    const float* sgW  = (const float*)d_in[8];
    const float* sgb  = (const float*)d_in[9];
    const float* vW   = (const float*)d_in[10];
    const float* vb   = (const float*)d_in[11];
    float* outg = (float*)d_out;

    dim3 grid(Bn * 8 / TPB);  // 4096 blocks of 256 threads; 8 lanes per graph
    gat_ppo_kernel<<<grid, TPB, 0, stream>>>(xg, adjg, Wg, ahg, wog, aog,
                                             muW, mub, sgW, sgb, vW, vb, outg);
}

// Round 19
// 49.075 us; speedup vs baseline: 2.3013x; 1.2620x over previous
//
#include <hip/hip_runtime.h>
#include <math.h>

#define TPB 256

constexpr int Bn    = 131072;
constexpr float LOG2E = 1.4426950408889634f;

typedef float v2f __attribute__((ext_vector_type(2)));

__global__ __launch_bounds__(TPB)
void gat_ppo_kernel(const float* __restrict__ xg,
                    const float* __restrict__ adjg,
                    const float* __restrict__ Wg,
                    const float* __restrict__ ahg,
                    const float* __restrict__ wog,
                    const float* __restrict__ aog,
                    const float* __restrict__ muWg,
                    const float* __restrict__ mubg,
                    const float* __restrict__ sgWg,
                    const float* __restrict__ sgbg,
                    const float* __restrict__ vWg,
                    const float* __restrict__ vbg,
                    float* __restrict__ outg)
{
    // R12: best verified kernel of the session (49.08 us). Merged f-pass +
    // 3 concurrent head phases; wave-local tiles; compiler fence pins the
    // cross-lane tile write->read order (round-9 race mechanism); log2-domain
    // no-max softmax; deferred normalization; s_load weight delivery.
    __shared__ float4 tile[4][3][200];

    const int lb = threadIdx.x;
    const int w  = lb >> 6;                 // wave id in block
    const int g  = (lb & 63) >> 3;          // graph within wave
    const int n  = lb & 7;                  // node id
    const size_t t = (size_t)blockIdx.x * TPB + lb;   // global row = b*8 + n

    // ---- adj row -> 8-bit mask ----
    unsigned amask;
    {
        const float4* a4 = (const float4*)(adjg) + t * 2;
        float4 a0 = a4[0], a1 = a4[1];
        amask =  (unsigned)(a0.x > 0.0f)
              | ((unsigned)(a0.y > 0.0f) << 1)
              | ((unsigned)(a0.z > 0.0f) << 2)
              | ((unsigned)(a0.w > 0.0f) << 3)
              | ((unsigned)(a1.x > 0.0f) << 4)
              | ((unsigned)(a1.y > 0.0f) << 5)
              | ((unsigned)(a1.z > 0.0f) << 6)
              | ((unsigned)(a1.w > 0.0f) << 7);
    }

    // ---- merged f-pass: all 3 heads' Wh accumulators in one x stream ----
    const v2f* Wp = (const v2f*)Wg;
    v2f acc[3][4];
    #pragma unroll
    for (int h = 0; h < 3; ++h)
        #pragma unroll
        for (int o2 = 0; o2 < 4; ++o2) acc[h][o2] = (v2f){0.0f, 0.0f};

    {
        const float2* xr = (const float2*)(xg + t * 30);
        #pragma unroll
        for (int k = 0; k < 15; ++k) {
            float2 v = xr[k];
            #pragma unroll
            for (int e = 0; e < 2; ++e) {
                const int f = 2 * k + e;
                const float xf = e ? v.y : v.x;
                v2f xv = (v2f){xf, xf};
                #pragma unroll
                for (int h = 0; h < 3; ++h)
                    #pragma unroll
                    for (int o2 = 0; o2 < 4; ++o2)
                        acc[h][o2] = __builtin_elementwise_fma(xv, Wp[h * 120 + f * 4 + o2], acc[h][o2]);
            }
        }
    }

    // ---- scores for all heads (log2 domain) ----
    float f1h[3], f2h[3];
    #pragma unroll
    for (int h = 0; h < 3; ++h) {
        float s1 = 0.0f, s2 = 0.0f;
        #pragma unroll
        for (int o2 = 0; o2 < 4; ++o2) {
            s1 = fmaf(acc[h][o2].x, ahg[h * 16 + 2 * o2],     s1);
            s1 = fmaf(acc[h][o2].y, ahg[h * 16 + 2 * o2 + 1], s1);
            s2 = fmaf(acc[h][o2].x, ahg[h * 16 + 8 + 2 * o2],     s2);
            s2 = fmaf(acc[h][o2].y, ahg[h * 16 + 8 + 2 * o2 + 1], s2);
        }
        f1h[h] = s1 * LOG2E;
        f2h[h] = s2 * LOG2E;
    }

    // ---- publish all 3 heads' Wh rows (6 x ds_write_b128) ----
    #pragma unroll
    for (int h = 0; h < 3; ++h) {
        tile[w][h][g * 25 + n * 3]     = (float4){acc[h][0].x, acc[h][0].y, acc[h][1].x, acc[h][1].y};
        tile[w][h][g * 25 + n * 3 + 1] = (float4){acc[h][2].x, acc[h][2].y, acc[h][3].x, acc[h][3].y};
    }
    // Compiler fence: tile reads below must not hoist above the writes
    // (cross-lane dependency invisible to alias analysis). HW: per-wave
    // in-order LDS pipe makes write->read safe once order is pinned.
    asm volatile("" ::: "memory");
    __builtin_amdgcn_sched_barrier(0);

    // ---- 3 softmaxes interleaved (24 independent shfl + exp chains) ----
    float p[3][8];
    float s[3] = {0.0f, 0.0f, 0.0f};
    #pragma unroll
    for (int m = 0; m < 8; ++m) {
        const bool on = (amask >> m) & 1u;
        #pragma unroll
        for (int h = 0; h < 3; ++h) {
            float ev = f1h[h] + __shfl(f2h[h], m, 8);
            ev = fmaxf(ev, 0.2f * ev);                 // leaky (log2-scaled)
            float pe = on ? __builtin_amdgcn_exp2f(ev) : 0.0f;
            p[h][m] = pe; s[h] += pe;
        }
    }

    // ---- 3 aggregations: 48 independent broadcast b128 reads ----
    v2f hacc[3][4];
    #pragma unroll
    for (int h = 0; h < 3; ++h)
        #pragma unroll
        for (int o2 = 0; o2 < 4; ++o2) hacc[h][o2] = (v2f){0.0f, 0.0f};

    #pragma unroll
    for (int m = 0; m < 8; ++m) {
        #pragma unroll
        for (int h = 0; h < 3; ++h) {
            float4 lo = tile[w][h][g * 25 + m * 3];
            float4 hi = tile[w][h][g * 25 + m * 3 + 1];
            v2f av = (v2f){p[h][m], p[h][m]};
            hacc[h][0] = __builtin_elementwise_fma(av, (v2f){lo.x, lo.y}, hacc[h][0]);
            hacc[h][1] = __builtin_elementwise_fma(av, (v2f){lo.z, lo.w}, hacc[h][1]);
            hacc[h][2] = __builtin_elementwise_fma(av, (v2f){hi.x, hi.y}, hacc[h][2]);
            hacc[h][3] = __builtin_elementwise_fma(av, (v2f){hi.z, hi.w}, hacc[h][3]);
        }
    }

    // ---- elu + W_out fold ----
    float wh2 = 0.0f;
    #pragma unroll
    for (int h = 0; h < 3; ++h) {
        float rs = 1.0f / s[h];
        #pragma unroll
        for (int o2 = 0; o2 < 4; ++o2) {
            #pragma unroll
            for (int j = 0; j < 2; ++j) {
                float hv = hacc[h][o2][j] * rs;
                hv = (hv > 0.0f) ? hv : (__expf(hv) - 1.0f);   // elu
                wh2 = fmaf(hv, wog[h * 8 + 2 * o2 + j], wh2);  // h @ W_out
            }
        }
    }

    // ---- second GAT layer on Wh2 (log2 domain, deferred norm) ----
    const float a0c = aog[0] * LOG2E, a1c = aog[1] * LOG2E;
    float wh2a[8];
    #pragma unroll
    for (int m = 0; m < 8; ++m) wh2a[m] = __shfl(wh2, m, 8);

    float g1 = a0c * wh2;
    float s2s = 0.0f;
    float og = 0.0f;
    #pragma unroll
    for (int m = 0; m < 8; ++m) {
        float ev = fmaf(a1c, wh2a[m], g1);
        ev = fmaxf(ev, 0.2f * ev);
        float pe = ((amask >> m) & 1u) ? __builtin_amdgcn_exp2f(ev) : 0.0f;
        s2s += pe;
        og = fmaf(pe, wh2a[m], og);
    }
    og /= s2s;
    float g2v = (og > 0.0f) ? og : (__expf(og) - 1.0f);   // elu -> g[b][n]

    // ---- MLP heads: mu, sigma (per node), value (per batch) ----
    v2f gp[4];
    #pragma unroll
    for (int m = 0; m < 4; ++m)
        gp[m] = (v2f){__shfl(g2v, 2 * m, 8), __shfl(g2v, 2 * m + 1, 8)};

    const v2f* muWp = (const v2f*)muWg;
    const v2f* sgWp = (const v2f*)sgWg;
    const v2f* vWp  = (const v2f*)vWg;
    v2f ma = (v2f){0.0f, 0.0f}, sa = (v2f){0.0f, 0.0f}, va = (v2f){0.0f, 0.0f};
    #pragma unroll
    for (int k = 0; k < 4; ++k) {
        ma = __builtin_elementwise_fma(gp[k], muWp[n * 4 + k], ma);
        sa = __builtin_elementwise_fma(gp[k], sgWp[n * 4 + k], sa);
        va = __builtin_elementwise_fma(gp[k], vWp[k],          va);
    }
    float mu = ma.x + ma.y + mubg[n];
    float sg = sa.x + sa.y + sgbg[n];
    float vv = va.x + va.y + vbg[0];

    mu = 1.0f / (1.0f + __expf(-mu));                               // sigmoid
    sg = fmaxf(sg, 0.0f) + log1pf(__expf(-fabsf(sg))) + 0.001f;     // softplus + 1e-3

    outg[t]          = mu;
    outg[Bn * 8 + t] = sg;
    if (n == 0) outg[Bn * 16 + (t >> 3)] = vv;
}

extern "C" void kernel_launch(void* const* d_in, const int* in_sizes, int n_in,
                              void* d_out, int out_size, void* d_ws, size_t ws_size,
                              hipStream_t stream) {
    const float* xg   = (const float*)d_in[0];
    const float* adjg = (const float*)d_in[1];
    const float* Wg   = (const float*)d_in[2];
    const float* ahg  = (const float*)d_in[3];
    const float* wog  = (const float*)d_in[4];
    const float* aog  = (const float*)d_in[5];
    const float* muW  = (const float*)d_in[6];
    const float* mub  = (const float*)d_in[7];
    const float* sgW  = (const float*)d_in[8];
    const float* sgb  = (const float*)d_in[9];
    const float* vW   = (const float*)d_in[10];
    const float* vb   = (const float*)d_in[11];
    float* outg = (float*)d_out;

    dim3 grid(Bn * 8 / TPB);  // 4096 blocks of 256 threads; 8 lanes per graph
    gat_ppo_kernel<<<grid, TPB, 0, stream>>>(xg, adjg, Wg, ahg, wog, aog,
                                             muW, mub, sgW, sgb, vW, vb, outg);
}

// Round 20
// 48.473 us; speedup vs baseline: 2.3298x; 1.0124x over previous
//
#include <hip/hip_runtime.h>
#include <math.h>

#define TPB 256

constexpr int Bn    = 131072;
constexpr float LOG2E = 1.4426950408889634f;

typedef float v2f __attribute__((ext_vector_type(2)));

__global__ __launch_bounds__(TPB)
void gat_ppo_kernel(const float* __restrict__ xg,
                    const float* __restrict__ adjg,
                    const float* __restrict__ Wg,
                    const float* __restrict__ ahg,
                    const float* __restrict__ wog,
                    const float* __restrict__ aog,
                    const float* __restrict__ muWg,
                    const float* __restrict__ mubg,
                    const float* __restrict__ sgWg,
                    const float* __restrict__ sgbg,
                    const float* __restrict__ vWg,
                    const float* __restrict__ vbg,
                    float* __restrict__ outg)
{
    // R12/R19 (49.07 us) with ONE change: the f2 cross-lane exchange rides in
    // the tile's spare float4 slot (stride is 3 slots/node, 2 used), and the
    // softmax is FUSED into the aggregation loop. This removes the 24-bpermute
    // phase entirely: post-publish there is now a single DS phase of
    // independent reads instead of two dependent round-trips.
    __shared__ float4 tile[4][3][200];

    const int lb = threadIdx.x;
    const int w  = lb >> 6;                 // wave id in block
    const int g  = (lb & 63) >> 3;          // graph within wave
    const int n  = lb & 7;                  // node id
    const size_t t = (size_t)blockIdx.x * TPB + lb;   // global row = b*8 + n

    // ---- adj row -> 8-bit mask ----
    unsigned amask;
    {
        const float4* a4 = (const float4*)(adjg) + t * 2;
        float4 a0 = a4[0], a1 = a4[1];
        amask =  (unsigned)(a0.x > 0.0f)
              | ((unsigned)(a0.y > 0.0f) << 1)
              | ((unsigned)(a0.z > 0.0f) << 2)
              | ((unsigned)(a0.w > 0.0f) << 3)
              | ((unsigned)(a1.x > 0.0f) << 4)
              | ((unsigned)(a1.y > 0.0f) << 5)
              | ((unsigned)(a1.z > 0.0f) << 6)
              | ((unsigned)(a1.w > 0.0f) << 7);
    }

    // ---- merged f-pass: all 3 heads' Wh accumulators in one x stream ----
    const v2f* Wp = (const v2f*)Wg;
    v2f acc[3][4];
    #pragma unroll
    for (int h = 0; h < 3; ++h)
        #pragma unroll
        for (int o2 = 0; o2 < 4; ++o2) acc[h][o2] = (v2f){0.0f, 0.0f};

    {
        const float2* xr = (const float2*)(xg + t * 30);
        #pragma unroll
        for (int k = 0; k < 15; ++k) {
            float2 v = xr[k];
            #pragma unroll
            for (int e = 0; e < 2; ++e) {
                const int f = 2 * k + e;
                const float xf = e ? v.y : v.x;
                v2f xv = (v2f){xf, xf};
                #pragma unroll
                for (int h = 0; h < 3; ++h)
                    #pragma unroll
                    for (int o2 = 0; o2 < 4; ++o2)
                        acc[h][o2] = __builtin_elementwise_fma(xv, Wp[h * 120 + f * 4 + o2], acc[h][o2]);
            }
        }
    }

    // ---- scores for all heads (log2 domain) ----
    float f1h[3], f2h[3];
    #pragma unroll
    for (int h = 0; h < 3; ++h) {
        float s1 = 0.0f, s2 = 0.0f;
        #pragma unroll
        for (int o2 = 0; o2 < 4; ++o2) {
            s1 = fmaf(acc[h][o2].x, ahg[h * 16 + 2 * o2],     s1);
            s1 = fmaf(acc[h][o2].y, ahg[h * 16 + 2 * o2 + 1], s1);
            s2 = fmaf(acc[h][o2].x, ahg[h * 16 + 8 + 2 * o2],     s2);
            s2 = fmaf(acc[h][o2].y, ahg[h * 16 + 8 + 2 * o2 + 1], s2);
        }
        f1h[h] = s1 * LOG2E;
        f2h[h] = s2 * LOG2E;
    }

    // ---- publish Wh rows + f2 into the spare slot (6 b128 + 3 b32 writes) ----
    #pragma unroll
    for (int h = 0; h < 3; ++h) {
        tile[w][h][g * 25 + n * 3]     = (float4){acc[h][0].x, acc[h][0].y, acc[h][1].x, acc[h][1].y};
        tile[w][h][g * 25 + n * 3 + 1] = (float4){acc[h][2].x, acc[h][2].y, acc[h][3].x, acc[h][3].y};
        ((float*)&tile[w][h][g * 25 + n * 3 + 2])[0] = f2h[h];
    }
    // Compiler fence: tile reads below must not hoist above the writes
    // (cross-lane dependency invisible to alias analysis). HW: per-wave
    // in-order LDS pipe makes write->read safe once order is pinned.
    asm volatile("" ::: "memory");
    __builtin_amdgcn_sched_barrier(0);

    // ---- FUSED softmax + aggregation: one phase of independent DS reads ----
    v2f hacc[3][4];
    float s[3] = {0.0f, 0.0f, 0.0f};
    #pragma unroll
    for (int h = 0; h < 3; ++h)
        #pragma unroll
        for (int o2 = 0; o2 < 4; ++o2) hacc[h][o2] = (v2f){0.0f, 0.0f};

    #pragma unroll
    for (int m = 0; m < 8; ++m) {
        const bool on = (amask >> m) & 1u;
        #pragma unroll
        for (int h = 0; h < 3; ++h) {
            float4 lo  = tile[w][h][g * 25 + m * 3];
            float4 hi  = tile[w][h][g * 25 + m * 3 + 1];
            float  f2m = ((const float*)&tile[w][h][g * 25 + m * 3 + 2])[0];
            float ev = f1h[h] + f2m;
            ev = fmaxf(ev, 0.2f * ev);                 // leaky (log2-scaled)
            float pe = on ? __builtin_amdgcn_exp2f(ev) : 0.0f;
            s[h] += pe;
            v2f av = (v2f){pe, pe};
            hacc[h][0] = __builtin_elementwise_fma(av, (v2f){lo.x, lo.y}, hacc[h][0]);
            hacc[h][1] = __builtin_elementwise_fma(av, (v2f){lo.z, lo.w}, hacc[h][1]);
            hacc[h][2] = __builtin_elementwise_fma(av, (v2f){hi.x, hi.y}, hacc[h][2]);
            hacc[h][3] = __builtin_elementwise_fma(av, (v2f){hi.z, hi.w}, hacc[h][3]);
        }
    }

    // ---- elu + W_out fold ----
    float wh2 = 0.0f;
    #pragma unroll
    for (int h = 0; h < 3; ++h) {
        float rs = 1.0f / s[h];
        #pragma unroll
        for (int o2 = 0; o2 < 4; ++o2) {
            #pragma unroll
            for (int j = 0; j < 2; ++j) {
                float hv = hacc[h][o2][j] * rs;
                hv = (hv > 0.0f) ? hv : (__expf(hv) - 1.0f);   // elu
                wh2 = fmaf(hv, wog[h * 8 + 2 * o2 + j], wh2);  // h @ W_out
            }
        }
    }

    // ---- second GAT layer on Wh2 (log2 domain, deferred norm) ----
    const float a0c = aog[0] * LOG2E, a1c = aog[1] * LOG2E;
    float wh2a[8];
    #pragma unroll
    for (int m = 0; m < 8; ++m) wh2a[m] = __shfl(wh2, m, 8);

    float g1 = a0c * wh2;
    float s2s = 0.0f;
    float og = 0.0f;
    #pragma unroll
    for (int m = 0; m < 8; ++m) {
        float ev = fmaf(a1c, wh2a[m], g1);
        ev = fmaxf(ev, 0.2f * ev);
        float pe = ((amask >> m) & 1u) ? __builtin_amdgcn_exp2f(ev) : 0.0f;
        s2s += pe;
        og = fmaf(pe, wh2a[m], og);
    }
    og /= s2s;
    float g2v = (og > 0.0f) ? og : (__expf(og) - 1.0f);   // elu -> g[b][n]

    // ---- MLP heads: mu, sigma (per node), value (per batch) ----
    v2f gp[4];
    #pragma unroll
    for (int m = 0; m < 4; ++m)
        gp[m] = (v2f){__shfl(g2v, 2 * m, 8), __shfl(g2v, 2 * m + 1, 8)};

    const v2f* muWp = (const v2f*)muWg;
    const v2f* sgWp = (const v2f*)sgWg;
    const v2f* vWp  = (const v2f*)vWg;
    v2f ma = (v2f){0.0f, 0.0f}, sa = (v2f){0.0f, 0.0f}, va = (v2f){0.0f, 0.0f};
    #pragma unroll
    for (int k = 0; k < 4; ++k) {
        ma = __builtin_elementwise_fma(gp[k], muWp[n * 4 + k], ma);
        sa = __builtin_elementwise_fma(gp[k], sgWp[n * 4 + k], sa);
        va = __builtin_elementwise_fma(gp[k], vWp[k],          va);
    }
    float mu = ma.x + ma.y + mubg[n];
    float sg = sa.x + sa.y + sgbg[n];
    float vv = va.x + va.y + vbg[0];

    mu = 1.0f / (1.0f + __expf(-mu));                               // sigmoid
    sg = fmaxf(sg, 0.0f) + log1pf(__expf(-fabsf(sg))) + 0.001f;     // softplus + 1e-3

    outg[t]          = mu;
    outg[Bn * 8 + t] = sg;
    if (n == 0) outg[Bn * 16 + (t >> 3)] = vv;
}

extern "C" void kernel_launch(void* const* d_in, const int* in_sizes, int n_in,
                              void* d_out, int out_size, void* d_ws, size_t ws_size,
                              hipStream_t stream) {
    const float* xg   = (const float*)d_in[0];
    const float* adjg = (const float*)d_in[1];
    const float* Wg   = (const float*)d_in[2];
    const float* ahg  = (const float*)d_in[3];
    const float* wog  = (const float*)d_in[4];
    const float* aog  = (const float*)d_in[5];
    const float* muW  = (const float*)d_in[6];
    const float* mub  = (const float*)d_in[7];
    const float* sgW  = (const float*)d_in[8];
    const float* sgb  = (const float*)d_in[9];
    const float* vW   = (const float*)d_in[10];
    const float* vb   = (const float*)d_in[11];
    float* outg = (float*)d_out;

    dim3 grid(Bn * 8 / TPB);  // 4096 blocks of 256 threads; 8 lanes per graph
    gat_ppo_kernel<<<grid, TPB, 0, stream>>>(xg, adjg, Wg, ahg, wog, aog,
                                             muW, mub, sgW, sgb, vW, vb, outg);
}